// Round 3
// baseline (505.870 us; speedup 1.0000x reference)
//
#include <hip/hip_runtime.h>
#include <hip/hip_bf16.h>

// ESA_SMILES fused pipeline for MI355X (gfx950).
// Identity: cap = LN(x)@W1^T+b1 ; feat = cap@W2^T+b2 = LN(x)@(W2W1)^T+(W2b1+b2)
// out[b,d] = sum_n exp(feat[n,d])*cap[n,d] / sum_n exp(feat[n,d])
//
// R8 = R5 base, two structural changes (R7's prefetch+setprio reverted: null/-):
//  - GEMM uses mfma_f32_32x32x16_bf16: measured 13% faster matrix pipe than
//    16x16x32 (2382 vs 2075 TF), half the MFMA instructions, half the lgkm
//    sync points, GEMM live-set ~96 regs (vs 124) -> compiler can pipeline B.
//  - persistent grid=512 (2 blocks/CU), static entry stride: amortizes 1664
//    block launches, removes the 0.25-round dispatch tail, lets entry phases
//    drift. No cross-entry register state (R6's spill trap avoided).
//  - epilogue: wave-uniform valid==64 fast path; 1-level shuffle reduction
//    (32x32 C layout spans full column in one lane pair).

typedef short short8 __attribute__((ext_vector_type(8)));   // 8 x bf16
typedef short short4v __attribute__((ext_vector_type(4)));
typedef float f32x4 __attribute__((ext_vector_type(4)));
typedef float f32x16 __attribute__((ext_vector_type(16)));

__device__ inline short f2bf(float f) {
    unsigned u = __float_as_uint(f);
    u += 0x7fffu + ((u >> 16) & 1u);     // round-to-nearest-even
    return (short)(u >> 16);
}

// packed offset for element (n, k) of a 512x512 weight matrix, laid out as
// the B-fragment order of mfma_f32_32x32x16_bf16:
//   tile t = n>>5 (16 tiles of 32 cols), k-chunk k0 = k>>4,
//   lane = ((k>>3)&1)*32 + (n&31), j = k&7.
// One (t,k0) chunk = 64 lanes x 8 bf16 = 1KB, lane-contiguous.
__device__ inline size_t packed32_off(int n, int k) {
    const int t = n >> 5, l31 = n & 31;
    const int k0 = k >> 4, half = (k >> 3) & 1, j = k & 7;
    return ((size_t)((t * 32 + k0) * 64 + half * 32 + l31)) * 8 + j;
}

// ---------------------------------------------------------------------------
// prep_all: ONE dispatch, role-split blocks (512 threads each):
//   blocks 0..63    : W12p = bf16(W2) @ bf16(W1) via MFMA -> packed32 layout
//   blocks 64..191  : W1 fp32 -> bf16, packed32 layout (W1p)
//   blocks 192..195 : b12 = W2@b1 + b2 (4 blocks x 128 rows, 4 thr/row)
//   block  196      : entries (binary search on sorted data_batch)
//   blocks 197..228 : zero num/den
// ---------------------------------------------------------------------------
#define PREP_GRID 229

__global__ __launch_bounds__(512)
void esa_prep_all(const float* __restrict__ W1, const float* __restrict__ W2,
                  const float* __restrict__ b1, const float* __restrict__ b2,
                  const int* __restrict__ db, int T, int B,
                  short* __restrict__ W1p, short* __restrict__ W12p,
                  float* __restrict__ b12, int4* __restrict__ entries, int maxent,
                  float* __restrict__ numden) {
    __shared__ int off[513];
    __shared__ int nch[512];
    __shared__ int scan[513];
    const int bid = blockIdx.x;
    const int tid = threadIdx.x;

    if (bid < 64) {
        // ---- W12 tile (64x64) via MFMA, converting fp32->bf16 on the fly
        const int ti = bid >> 3, tj = bid & 7;
        const int wave = tid >> 6;          // 0..7
        const int lane = tid & 63;
        const int quad = lane >> 4;
        const int l16 = lane & 15;
        const int mhalf = wave >> 2;        // rows half (m-tiles 0-1 or 2-3)
        const int kq = wave & 3;
        const int kcol = tj * 64 + kq * 16 + l16;

        f32x4 acc[2];
        acc[0] = (f32x4)0.0f; acc[1] = (f32x4)0.0f;
        for (int j0 = 0; j0 < 512; j0 += 32) {
            short8 bfr;
#pragma unroll
            for (int jj = 0; jj < 8; ++jj)
                bfr[jj] = f2bf(W1[(size_t)(j0 + quad * 8 + jj) * 512 + kcol]);
#pragma unroll
            for (int mt = 0; mt < 2; ++mt) {
                const float* ar = W2 + (size_t)(ti * 64 + (mhalf * 2 + mt) * 16 + l16) * 512 +
                                  j0 + quad * 8;
                const float4 a0 = *(const float4*)ar;
                const float4 a1 = *(const float4*)(ar + 4);
                short8 afr = {f2bf(a0.x), f2bf(a0.y), f2bf(a0.z), f2bf(a0.w),
                              f2bf(a1.x), f2bf(a1.y), f2bf(a1.z), f2bf(a1.w)};
                acc[mt] = __builtin_amdgcn_mfma_f32_16x16x32_bf16(afr, bfr,
                                                                  acc[mt], 0, 0, 0);
            }
        }
        // C/D layout (16x16): col(k)=lane&15, row(n)=quad*4+r -> packed32 store
#pragma unroll
        for (int mt = 0; mt < 2; ++mt)
#pragma unroll
            for (int r = 0; r < 4; ++r) {
                const int n = ti * 64 + (mhalf * 2 + mt) * 16 + quad * 4 + r;
                W12p[packed32_off(n, kcol)] = f2bf(acc[mt][r]);
            }
    } else if (bid < 192) {
        // ---- W1 -> bf16, packed32. 4 consecutive k share a packed short4 slot.
        const int gid = (bid - 64) * 512 + tid;
        const int i4 = gid * 4;
        const int n = i4 >> 9, k = i4 & 511;
        const float4 a = *(const float4*)(W1 + i4);
        short4v sa = {f2bf(a.x), f2bf(a.y), f2bf(a.z), f2bf(a.w)};
        *(short4v*)(W1p + packed32_off(n, k)) = sa;
    } else if (bid < 196) {
        // ---- b12 = W2@b1 + b2 : 4 blocks x 128 rows, 4 threads per row
        const int row = (bid - 192) * 128 + (tid >> 2);
        const int part = tid & 3;
        const float* wr = W2 + (size_t)row * 512;
        float acc = 0.0f;
#pragma unroll 4
        for (int i = 0; i < 32; ++i) {
            const float4 w = *(const float4*)(wr + (i * 4 + part) * 4);
            const float4 bb = *(const float4*)(b1 + (i * 4 + part) * 4);
            acc += w.x * bb.x + w.y * bb.y + w.z * bb.z + w.w * bb.w;
        }
        acc += __shfl_xor(acc, 1);
        acc += __shfl_xor(acc, 2);
        if (part == 0) b12[row] = acc + b2[row];
    } else if (bid == 196) {
        // ---- entries
        for (int t = tid; t <= B; t += 512) {
            if (t == B) {
                off[t] = T;
            } else {
                int lo = 0, hi = T;
                while (lo < hi) {
                    int mid = (lo + hi) >> 1;
                    if (db[mid] < t) lo = mid + 1; else hi = mid;
                }
                off[t] = lo;
            }
        }
        __syncthreads();
        for (int t = tid; t < B; t += 512)
            nch[t] = (off[t + 1] - off[t] + 63) >> 6;
        __syncthreads();
        if (tid == 0) {
            int s = 0;
            for (int i = 0; i < B; ++i) { scan[i] = s; s += nch[i]; }
            scan[B] = s;
        }
        __syncthreads();
        for (int t = tid; t < B; t += 512) {
            int cnt = off[t + 1] - off[t];
            for (int j = 0; j < nch[t]; ++j) {
                int v = cnt - j * 64;
                if (v > 64) v = 64;
                entries[scan[t] + j] = make_int4(t, off[t] + j * 64, v, 0);
            }
        }
        int total = scan[B];
        for (int i = total + tid; i < maxent; i += 512)
            entries[i] = make_int4(0, 0, 0, 0);
    } else {
        // ---- zero num/den (2*B*512 floats = 131072)
        const int idx = (bid - 197) * 512 + tid;   // 0..16383
        float4 z = {0.0f, 0.0f, 0.0f, 0.0f};
        *(float4*)(numden + (size_t)idx * 8) = z;
        *(float4*)(numden + (size_t)idx * 8 + 4) = z;
    }
}

// ---------------------------------------------------------------------------
// Main fused kernel: PERSISTENT blocks (grid=512, 2 blocks/CU via 64KB LDS),
// static entry stride. Per entry:
//   Phase 1: LayerNorm, branch-free, 4-row ILP groups, XOR(m&15)-swizzled LDS.
//   Phase 2: dual GEMM with mfma_f32_32x32x16_bf16. Wave owns 64 cols as two
//     32-col tiles; per k-step: 2 A ds_read_b128 + 2 packed B loads + 4 MFMA.
//   Epilogue: e=exp(feat); column sums via one shfl_xor(32); 2 atomics/col.
// ---------------------------------------------------------------------------
__global__ __launch_bounds__(512, 4)
void esa_fused(const float* __restrict__ x, const float* __restrict__ gamma,
               const float* __restrict__ beta, const short* __restrict__ W1p,
               const short* __restrict__ W12p, const float* __restrict__ b1,
               const float* __restrict__ b12, const int4* __restrict__ entries,
               int nent, float* __restrict__ num, float* __restrict__ den) {
    __shared__ short ylds[64 * 512];   // 65,536 B exactly -> 2 blocks/CU
    const int tid = threadIdx.x;
    const int wave = tid >> 6;          // 0..7
    const int lane = tid & 63;
    const int l31 = lane & 31;
    const int hi = lane >> 5;
    const int xr = l31 & 15;            // read-side swizzle key (row = l31)
    const short* abase = ylds + (size_t)l31 * 512;

    for (int ent = blockIdx.x; ent < nent; ent += gridDim.x) {
        const int4 e = entries[ent];
        const int bat = e.x, start = e.y, valid = e.z;
        if (valid <= 0) continue;      // padded entry (uniform per block)

        // ---- Phase 1: LayerNorm, rows wave*8..+7, lane owns 8 cols.
        const float4 g0 = *(const float4*)(gamma + lane * 8);
        const float4 g1 = *(const float4*)(gamma + lane * 8 + 4);
        const float4 be0 = *(const float4*)(beta + lane * 8);
        const float4 be1 = *(const float4*)(beta + lane * 8 + 4);

#pragma unroll
        for (int g = 0; g < 2; ++g) {           // two ILP groups of 4 rows
            float4 ra[4], rb[4];
            float s[4], ss[4];
#pragma unroll
            for (int r = 0; r < 4; ++r) {
                const int m = wave * 8 + g * 4 + r;
                const int mc = m < valid ? m : valid - 1;   // clamp: in-batch
                const float* xr_ = x + (size_t)(start + mc) * 512 + lane * 8;
                ra[r] = *(const float4*)xr_;
                rb[r] = *(const float4*)(xr_ + 4);
            }
#pragma unroll
            for (int r = 0; r < 4; ++r) {
                s[r] = ra[r].x + ra[r].y + ra[r].z + ra[r].w +
                       rb[r].x + rb[r].y + rb[r].z + rb[r].w;
                ss[r] = ra[r].x * ra[r].x + ra[r].y * ra[r].y + ra[r].z * ra[r].z +
                        ra[r].w * ra[r].w + rb[r].x * rb[r].x + rb[r].y * rb[r].y +
                        rb[r].z * rb[r].z + rb[r].w * rb[r].w;
            }
#pragma unroll
            for (int o = 1; o <= 32; o <<= 1) { // 4 interleaved chains
#pragma unroll
                for (int r = 0; r < 4; ++r) {
                    s[r] += __shfl_xor(s[r], o);
                    ss[r] += __shfl_xor(ss[r], o);
                }
            }
            if (g == 0) __syncthreads();  // prev entry's GEMM LDS reads done
#pragma unroll
            for (int r = 0; r < 4; ++r) {
                const int m = wave * 8 + g * 4 + r;
                const float mu = s[r] * (1.0f / 512.0f);
                const float var = ss[r] * (1.0f / 512.0f) - mu * mu;
                const float rstd = rsqrtf(var + 1e-5f);
                short8 outv;
                outv[0] = f2bf((ra[r].x - mu) * rstd * g0.x + be0.x);
                outv[1] = f2bf((ra[r].y - mu) * rstd * g0.y + be0.y);
                outv[2] = f2bf((ra[r].z - mu) * rstd * g0.z + be0.z);
                outv[3] = f2bf((ra[r].w - mu) * rstd * g0.w + be0.w);
                outv[4] = f2bf((rb[r].x - mu) * rstd * g1.x + be1.x);
                outv[5] = f2bf((rb[r].y - mu) * rstd * g1.y + be1.y);
                outv[6] = f2bf((rb[r].z - mu) * rstd * g1.z + be1.z);
                outv[7] = f2bf((rb[r].w - mu) * rstd * g1.w + be1.w);
                // XOR swizzle: 16B block `lane` stored at lane ^ (m&15)
                *(short8*)&ylds[m * 512 + ((lane ^ (m & 15)) * 8)] = outv;
            }
        }
        __syncthreads();

        // ---- Phase 2: dual GEMM (32x32x16) + epilogue. Wave: cols wave*64..+63.
        const bool full = (valid >= 64);

        for (int grp = 0; grp < 2; ++grp) {
            const int nt32 = wave * 2 + grp;     // 32-col tile index, 0..15
            const short* w1 = W1p + (size_t)nt32 * 16384 + lane * 8;
            const short* w2 = W12p + (size_t)nt32 * 16384 + lane * 8;
            f32x16 acc_c[2], acc_f[2];
#pragma unroll
            for (int mt = 0; mt < 2; ++mt) {
                acc_c[mt] = (f32x16)0.0f;
                acc_f[mt] = (f32x16)0.0f;
            }
#pragma unroll 4
            for (int ks = 0; ks < 32; ++ks) {
                // A-frags: row = mt*32 + l31, k = ks*16 + hi*8 + j
                const int blk = ((ks << 1) | hi) ^ xr;
                const short* ap = abase + blk * 8;
                const short8 a0 = *(const short8*)(ap);
                const short8 a1 = *(const short8*)(ap + 32 * 512);
                const short8 bc = *(const short8*)(w1 + ks * 512);
                const short8 bf = *(const short8*)(w2 + ks * 512);
                acc_c[0] = __builtin_amdgcn_mfma_f32_32x32x16_bf16(
                    a0, bc, acc_c[0], 0, 0, 0);
                acc_c[1] = __builtin_amdgcn_mfma_f32_32x32x16_bf16(
                    a1, bc, acc_c[1], 0, 0, 0);
                acc_f[0] = __builtin_amdgcn_mfma_f32_32x32x16_bf16(
                    a0, bf, acc_f[0], 0, 0, 0);
                acc_f[1] = __builtin_amdgcn_mfma_f32_32x32x16_bf16(
                    a1, bf, acc_f[1], 0, 0, 0);
            }
            // Epilogue. C/D layout (m74/m101): col = lane&31,
            // row = (reg&3) + 8*(reg>>2) + 4*(lane>>5), reg in [0,16).
            const int n = wave * 64 + grp * 32 + l31;
            const float bb1 = b1[n];
            const float bb2 = b12[n];
            float se = 0.0f, sec = 0.0f;
            if (full) {
#pragma unroll
                for (int mt = 0; mt < 2; ++mt) {
#pragma unroll
                    for (int r = 0; r < 16; ++r) {
                        const float cap = acc_c[mt][r] + bb1;
                        const float ev = __expf(acc_f[mt][r] + bb2);
                        se += ev;
                        sec += ev * cap;
                    }
                }
            } else {
#pragma unroll
                for (int mt = 0; mt < 2; ++mt) {
#pragma unroll
                    for (int r = 0; r < 16; ++r) {
                        const int m = mt * 32 + (r & 3) + 8 * (r >> 2) + 4 * hi;
                        if (m < valid) {
                            const float cap = acc_c[mt][r] + bb1;
                            const float ev = __expf(acc_f[mt][r] + bb2);
                            se += ev;
                            sec += ev * cap;
                        }
                    }
                }
            }
            // lanes l and l+32 hold disjoint row sets of column n
            se += __shfl_xor(se, 32);
            sec += __shfl_xor(sec, 32);
            if (hi == 0) atomicAdd(&den[(size_t)bat * 512 + n], se);
            else atomicAdd(&num[(size_t)bat * 512 + n], sec);
        }
    }
}

__global__ __launch_bounds__(256)
void esa_finalize(const float* __restrict__ num, const float* __restrict__ den,
                  float* __restrict__ out, int n) {
    const int i = blockIdx.x * 256 + threadIdx.x;
    if (i < n) {
        const float d = den[i];
        out[i] = d > 0.0f ? num[i] / d : 0.0f;
    }
}

extern "C" void kernel_launch(void* const* d_in, const int* in_sizes, int n_in,
                              void* d_out, int out_size, void* d_ws, size_t ws_size,
                              hipStream_t stream) {
    const float* x = (const float*)d_in[0];
    const int* db = (const int*)d_in[1];
    // d_in[2] = max_nodes (unused: chunking derived from actual counts)
    const float* gamma = (const float*)d_in[3];
    const float* beta = (const float*)d_in[4];
    const float* W1 = (const float*)d_in[5];
    const float* b1 = (const float*)d_in[6];
    const float* W2 = (const float*)d_in[7];
    const float* b2 = (const float*)d_in[8];
    float* out = (float*)d_out;

    const int C = in_sizes[3];        // 512
    const int D = in_sizes[6];        // 512
    const int T = in_sizes[0] / C;    // 131072
    const int B = out_size / D;       // 128
    const int maxent = B + (T + 63) / 64;   // 2176

    char* ws = (char*)d_ws;
    short* W1p = (short*)(ws);                      // 512 KB packed
    short* W12p = (short*)(ws + 524288);            // 512 KB packed
    float* b12 = (float*)(ws + 1048576);            // 2 KB
    int4* entries = (int4*)(ws + 1050624);          // maxent*16
    size_t numoff = (1050624 + (size_t)maxent * 16 + 255) & ~(size_t)255;
    float* num = (float*)(ws + numoff);             // B*D*4
    float* den = (float*)(ws + numoff + (size_t)B * D * 4);

    esa_prep_all<<<PREP_GRID, 512, 0, stream>>>(W1, W2, b1, b2, db, T, B,
                                                W1p, W12p, b12, entries, maxent,
                                                num);
    esa_fused<<<512, 512, 0, stream>>>(x, gamma, beta, W1p, W12p, b1, b12,
                                       entries, maxent, num, den);
    esa_finalize<<<(B * D + 255) / 256, 256, 0, stream>>>(num, den, out, B * D);
}

// Round 4
// 482.215 us; speedup vs baseline: 1.0491x; 1.0491x over previous
//
#include <hip/hip_runtime.h>
#include <hip/hip_bf16.h>

// ESA_SMILES fused pipeline for MI355X (gfx950).
// Identity: cap = LN(x)@W1^T+b1 ; feat = cap@W2^T+b2 = LN(x)@(W2W1)^T+(W2b1+b2)
// out[b,d] = sum_n exp(feat[n,d])*cap[n,d] / sum_n exp(feat[n,d])
//
// R9 = R5 launch structure + R8's 32x32 MFMA path (clean A/B):
//  - R8 post-mortem: matrix cycles DID shrink to the 32x32 floor (145K vs
//    141K cy/CU), but the persistent lockstep grid lost cross-block phase
//    stagger (both utils fell together). So: keep fresh blocks, grid=maxent,
//    one entry per block (R5's proven stagger), keep the 32x32 GEMM and the
//    conflict-free ^(m&15) swizzle (SQ_LDS_BANK_CONFLICT: 8.6M -> 0 in R8).
//  - epilogue: wave-uniform valid==64 fast path; single shfl_xor(32) reduce.

typedef short short8 __attribute__((ext_vector_type(8)));   // 8 x bf16
typedef short short4v __attribute__((ext_vector_type(4)));
typedef float f32x4 __attribute__((ext_vector_type(4)));
typedef float f32x16 __attribute__((ext_vector_type(16)));

__device__ inline short f2bf(float f) {
    unsigned u = __float_as_uint(f);
    u += 0x7fffu + ((u >> 16) & 1u);     // round-to-nearest-even
    return (short)(u >> 16);
}

// packed offset for element (n, k) of a 512x512 weight matrix, laid out as
// the B-fragment order of mfma_f32_32x32x16_bf16:
//   tile t = n>>5 (16 tiles of 32 cols), k-chunk k0 = k>>4,
//   lane = ((k>>3)&1)*32 + (n&31), j = k&7.
// One (t,k0) chunk = 64 lanes x 8 bf16 = 1KB, lane-contiguous.
__device__ inline size_t packed32_off(int n, int k) {
    const int t = n >> 5, l31 = n & 31;
    const int k0 = k >> 4, half = (k >> 3) & 1, j = k & 7;
    return ((size_t)((t * 32 + k0) * 64 + half * 32 + l31)) * 8 + j;
}

// ---------------------------------------------------------------------------
// prep_all: ONE dispatch, role-split blocks (512 threads each):
//   blocks 0..63    : W12p = bf16(W2) @ bf16(W1) via MFMA -> packed32 layout
//   blocks 64..191  : W1 fp32 -> bf16, packed32 layout (W1p)
//   blocks 192..195 : b12 = W2@b1 + b2 (4 blocks x 128 rows, 4 thr/row)
//   block  196      : entries (binary search on sorted data_batch)
//   blocks 197..228 : zero num/den
// ---------------------------------------------------------------------------
#define PREP_GRID 229

__global__ __launch_bounds__(512)
void esa_prep_all(const float* __restrict__ W1, const float* __restrict__ W2,
                  const float* __restrict__ b1, const float* __restrict__ b2,
                  const int* __restrict__ db, int T, int B,
                  short* __restrict__ W1p, short* __restrict__ W12p,
                  float* __restrict__ b12, int4* __restrict__ entries, int maxent,
                  float* __restrict__ numden) {
    __shared__ int off[513];
    __shared__ int nch[512];
    __shared__ int scan[513];
    const int bid = blockIdx.x;
    const int tid = threadIdx.x;

    if (bid < 64) {
        // ---- W12 tile (64x64) via MFMA, converting fp32->bf16 on the fly
        const int ti = bid >> 3, tj = bid & 7;
        const int wave = tid >> 6;          // 0..7
        const int lane = tid & 63;
        const int quad = lane >> 4;
        const int l16 = lane & 15;
        const int mhalf = wave >> 2;        // rows half (m-tiles 0-1 or 2-3)
        const int kq = wave & 3;
        const int kcol = tj * 64 + kq * 16 + l16;

        f32x4 acc[2];
        acc[0] = (f32x4)0.0f; acc[1] = (f32x4)0.0f;
        for (int j0 = 0; j0 < 512; j0 += 32) {
            short8 bfr;
#pragma unroll
            for (int jj = 0; jj < 8; ++jj)
                bfr[jj] = f2bf(W1[(size_t)(j0 + quad * 8 + jj) * 512 + kcol]);
#pragma unroll
            for (int mt = 0; mt < 2; ++mt) {
                const float* ar = W2 + (size_t)(ti * 64 + (mhalf * 2 + mt) * 16 + l16) * 512 +
                                  j0 + quad * 8;
                const float4 a0 = *(const float4*)ar;
                const float4 a1 = *(const float4*)(ar + 4);
                short8 afr = {f2bf(a0.x), f2bf(a0.y), f2bf(a0.z), f2bf(a0.w),
                              f2bf(a1.x), f2bf(a1.y), f2bf(a1.z), f2bf(a1.w)};
                acc[mt] = __builtin_amdgcn_mfma_f32_16x16x32_bf16(afr, bfr,
                                                                  acc[mt], 0, 0, 0);
            }
        }
        // C/D layout (16x16): col(k)=lane&15, row(n)=quad*4+r -> packed32 store
#pragma unroll
        for (int mt = 0; mt < 2; ++mt)
#pragma unroll
            for (int r = 0; r < 4; ++r) {
                const int n = ti * 64 + (mhalf * 2 + mt) * 16 + quad * 4 + r;
                W12p[packed32_off(n, kcol)] = f2bf(acc[mt][r]);
            }
    } else if (bid < 192) {
        // ---- W1 -> bf16, packed32. 4 consecutive k share a packed short4 slot.
        const int gid = (bid - 64) * 512 + tid;
        const int i4 = gid * 4;
        const int n = i4 >> 9, k = i4 & 511;
        const float4 a = *(const float4*)(W1 + i4);
        short4v sa = {f2bf(a.x), f2bf(a.y), f2bf(a.z), f2bf(a.w)};
        *(short4v*)(W1p + packed32_off(n, k)) = sa;
    } else if (bid < 196) {
        // ---- b12 = W2@b1 + b2 : 4 blocks x 128 rows, 4 threads per row
        const int row = (bid - 192) * 128 + (tid >> 2);
        const int part = tid & 3;
        const float* wr = W2 + (size_t)row * 512;
        float acc = 0.0f;
#pragma unroll 4
        for (int i = 0; i < 32; ++i) {
            const float4 w = *(const float4*)(wr + (i * 4 + part) * 4);
            const float4 bb = *(const float4*)(b1 + (i * 4 + part) * 4);
            acc += w.x * bb.x + w.y * bb.y + w.z * bb.z + w.w * bb.w;
        }
        acc += __shfl_xor(acc, 1);
        acc += __shfl_xor(acc, 2);
        if (part == 0) b12[row] = acc + b2[row];
    } else if (bid == 196) {
        // ---- entries
        for (int t = tid; t <= B; t += 512) {
            if (t == B) {
                off[t] = T;
            } else {
                int lo = 0, hi = T;
                while (lo < hi) {
                    int mid = (lo + hi) >> 1;
                    if (db[mid] < t) lo = mid + 1; else hi = mid;
                }
                off[t] = lo;
            }
        }
        __syncthreads();
        for (int t = tid; t < B; t += 512)
            nch[t] = (off[t + 1] - off[t] + 63) >> 6;
        __syncthreads();
        if (tid == 0) {
            int s = 0;
            for (int i = 0; i < B; ++i) { scan[i] = s; s += nch[i]; }
            scan[B] = s;
        }
        __syncthreads();
        for (int t = tid; t < B; t += 512) {
            int cnt = off[t + 1] - off[t];
            for (int j = 0; j < nch[t]; ++j) {
                int v = cnt - j * 64;
                if (v > 64) v = 64;
                entries[scan[t] + j] = make_int4(t, off[t] + j * 64, v, 0);
            }
        }
        int total = scan[B];
        for (int i = total + tid; i < maxent; i += 512)
            entries[i] = make_int4(0, 0, 0, 0);
    } else {
        // ---- zero num/den (2*B*512 floats = 131072)
        const int idx = (bid - 197) * 512 + tid;   // 0..16383
        float4 z = {0.0f, 0.0f, 0.0f, 0.0f};
        *(float4*)(numden + (size_t)idx * 8) = z;
        *(float4*)(numden + (size_t)idx * 8 + 4) = z;
    }
}

// ---------------------------------------------------------------------------
// Main fused kernel: one block = 64 nodes of one batch, 512 threads (8 waves),
// 2 blocks/CU (LDS exactly 64KB) -> 16 waves/CU. Fresh blocks, grid=maxent
// (natural cross-block phase stagger on each CU).
// Phase 1: LayerNorm, branch-free, 4-row ILP groups, XOR(m&15)-swizzled LDS.
// Phase 2: dual GEMM with mfma_f32_32x32x16_bf16 (32.3 cyc/instr vs 16x16's
//   19.4 for half the instructions = -17% matrix-pipe time). Wave owns 64
//   cols as two 32-col tiles; per k-step: 2 ds_read_b128 (conflict-free) +
//   2 packed lane-contiguous 1KB B loads + 4 MFMA.
// Epilogue: e=exp(feat); column sums via one shfl_xor(32); 2 atomics/col.
// ---------------------------------------------------------------------------
__global__ __launch_bounds__(512, 4)
void esa_fused(const float* __restrict__ x, const float* __restrict__ gamma,
               const float* __restrict__ beta, const short* __restrict__ W1p,
               const short* __restrict__ W12p, const float* __restrict__ b1,
               const float* __restrict__ b12, const int4* __restrict__ entries,
               float* __restrict__ num, float* __restrict__ den) {
    __shared__ short ylds[64 * 512];   // 65,536 B exactly -> 2 blocks/CU
    const int4 e = entries[blockIdx.x];
    const int bat = e.x, start = e.y, valid = e.z;
    if (valid <= 0) return;

    const int tid = threadIdx.x;
    const int wave = tid >> 6;          // 0..7
    const int lane = tid & 63;
    const int l31 = lane & 31;
    const int hi = lane >> 5;

    // ---- Phase 1: LayerNorm, rows wave*8..+7, lane owns 8 cols. Branch-free.
    const float4 g0 = *(const float4*)(gamma + lane * 8);
    const float4 g1 = *(const float4*)(gamma + lane * 8 + 4);
    const float4 be0 = *(const float4*)(beta + lane * 8);
    const float4 be1 = *(const float4*)(beta + lane * 8 + 4);

#pragma unroll
    for (int g = 0; g < 2; ++g) {               // two ILP groups of 4 rows
        float4 ra[4], rb[4];
        float s[4], ss[4];
#pragma unroll
        for (int r = 0; r < 4; ++r) {
            const int m = wave * 8 + g * 4 + r;
            const int mc = m < valid ? m : valid - 1;   // clamp: always in-batch
            const float* xr_ = x + (size_t)(start + mc) * 512 + lane * 8;
            ra[r] = *(const float4*)xr_;
            rb[r] = *(const float4*)(xr_ + 4);
        }
#pragma unroll
        for (int r = 0; r < 4; ++r) {
            s[r] = ra[r].x + ra[r].y + ra[r].z + ra[r].w +
                   rb[r].x + rb[r].y + rb[r].z + rb[r].w;
            ss[r] = ra[r].x * ra[r].x + ra[r].y * ra[r].y + ra[r].z * ra[r].z +
                    ra[r].w * ra[r].w + rb[r].x * rb[r].x + rb[r].y * rb[r].y +
                    rb[r].z * rb[r].z + rb[r].w * rb[r].w;
        }
#pragma unroll
        for (int o = 1; o <= 32; o <<= 1) {     // 4 interleaved chains
#pragma unroll
            for (int r = 0; r < 4; ++r) {
                s[r] += __shfl_xor(s[r], o);
                ss[r] += __shfl_xor(ss[r], o);
            }
        }
#pragma unroll
        for (int r = 0; r < 4; ++r) {
            const int m = wave * 8 + g * 4 + r;
            const float mu = s[r] * (1.0f / 512.0f);
            const float var = ss[r] * (1.0f / 512.0f) - mu * mu;
            const float rstd = rsqrtf(var + 1e-5f);
            short8 outv;
            outv[0] = f2bf((ra[r].x - mu) * rstd * g0.x + be0.x);
            outv[1] = f2bf((ra[r].y - mu) * rstd * g0.y + be0.y);
            outv[2] = f2bf((ra[r].z - mu) * rstd * g0.z + be0.z);
            outv[3] = f2bf((ra[r].w - mu) * rstd * g0.w + be0.w);
            outv[4] = f2bf((rb[r].x - mu) * rstd * g1.x + be1.x);
            outv[5] = f2bf((rb[r].y - mu) * rstd * g1.y + be1.y);
            outv[6] = f2bf((rb[r].z - mu) * rstd * g1.z + be1.z);
            outv[7] = f2bf((rb[r].w - mu) * rstd * g1.w + be1.w);
            // XOR swizzle: 16B block `lane` stored at lane ^ (m&15)
            *(short8*)&ylds[m * 512 + ((lane ^ (m & 15)) * 8)] = outv;
        }
    }
    __syncthreads();

    // ---- Phase 2: dual GEMM (32x32x16) + epilogue. Wave: cols wave*64..+63.
    const int xr = l31 & 15;                 // read-side swizzle key (row = l31)
    const short* abase = ylds + (size_t)l31 * 512;
    const bool full = (valid >= 64);

    for (int grp = 0; grp < 2; ++grp) {
        const int nt32 = wave * 2 + grp;     // 32-col tile index, 0..15
        const short* w1 = W1p + (size_t)nt32 * 16384 + lane * 8;
        const short* w2 = W12p + (size_t)nt32 * 16384 + lane * 8;
        f32x16 acc_c[2], acc_f[2];
#pragma unroll
        for (int mt = 0; mt < 2; ++mt) {
            acc_c[mt] = (f32x16)0.0f;
            acc_f[mt] = (f32x16)0.0f;
        }
#pragma unroll 4
        for (int ks = 0; ks < 32; ++ks) {
            // A-frags: row = mt*32 + l31, k = ks*16 + hi*8 + j
            const int blk = ((ks << 1) | hi) ^ xr;
            const short* ap = abase + blk * 8;
            const short8 a0 = *(const short8*)(ap);
            const short8 a1 = *(const short8*)(ap + 32 * 512);
            const short8 bc = *(const short8*)(w1 + ks * 512);
            const short8 bf = *(const short8*)(w2 + ks * 512);
            acc_c[0] = __builtin_amdgcn_mfma_f32_32x32x16_bf16(
                a0, bc, acc_c[0], 0, 0, 0);
            acc_c[1] = __builtin_amdgcn_mfma_f32_32x32x16_bf16(
                a1, bc, acc_c[1], 0, 0, 0);
            acc_f[0] = __builtin_amdgcn_mfma_f32_32x32x16_bf16(
                a0, bf, acc_f[0], 0, 0, 0);
            acc_f[1] = __builtin_amdgcn_mfma_f32_32x32x16_bf16(
                a1, bf, acc_f[1], 0, 0, 0);
        }
        // Epilogue. C/D layout (m74/m101): col = lane&31,
        // row = (reg&3) + 8*(reg>>2) + 4*(lane>>5), reg in [0,16).
        const int n = wave * 64 + grp * 32 + l31;
        const float bb1 = b1[n];
        const float bb2 = b12[n];
        float se = 0.0f, sec = 0.0f;
        if (full) {
#pragma unroll
            for (int mt = 0; mt < 2; ++mt) {
#pragma unroll
                for (int r = 0; r < 16; ++r) {
                    const float cap = acc_c[mt][r] + bb1;
                    const float ev = __expf(acc_f[mt][r] + bb2);
                    se += ev;
                    sec += ev * cap;
                }
            }
        } else {
#pragma unroll
            for (int mt = 0; mt < 2; ++mt) {
#pragma unroll
                for (int r = 0; r < 16; ++r) {
                    const int m = mt * 32 + (r & 3) + 8 * (r >> 2) + 4 * hi;
                    if (m < valid) {
                        const float cap = acc_c[mt][r] + bb1;
                        const float ev = __expf(acc_f[mt][r] + bb2);
                        se += ev;
                        sec += ev * cap;
                    }
                }
            }
        }
        // lanes l and l+32 hold disjoint row sets of column n
        se += __shfl_xor(se, 32);
        sec += __shfl_xor(sec, 32);
        if (hi == 0) atomicAdd(&den[(size_t)bat * 512 + n], se);
        else atomicAdd(&num[(size_t)bat * 512 + n], sec);
    }
}

__global__ __launch_bounds__(256)
void esa_finalize(const float* __restrict__ num, const float* __restrict__ den,
                  float* __restrict__ out, int n) {
    const int i = blockIdx.x * 256 + threadIdx.x;
    if (i < n) {
        const float d = den[i];
        out[i] = d > 0.0f ? num[i] / d : 0.0f;
    }
}

extern "C" void kernel_launch(void* const* d_in, const int* in_sizes, int n_in,
                              void* d_out, int out_size, void* d_ws, size_t ws_size,
                              hipStream_t stream) {
    const float* x = (const float*)d_in[0];
    const int* db = (const int*)d_in[1];
    // d_in[2] = max_nodes (unused: chunking derived from actual counts)
    const float* gamma = (const float*)d_in[3];
    const float* beta = (const float*)d_in[4];
    const float* W1 = (const float*)d_in[5];
    const float* b1 = (const float*)d_in[6];
    const float* W2 = (const float*)d_in[7];
    const float* b2 = (const float*)d_in[8];
    float* out = (float*)d_out;

    const int C = in_sizes[3];        // 512
    const int D = in_sizes[6];        // 512
    const int T = in_sizes[0] / C;    // 131072
    const int B = out_size / D;       // 128
    const int maxent = B + (T + 63) / 64;   // 2176

    char* ws = (char*)d_ws;
    short* W1p = (short*)(ws);                      // 512 KB packed
    short* W12p = (short*)(ws + 524288);            // 512 KB packed
    float* b12 = (float*)(ws + 1048576);            // 2 KB
    int4* entries = (int4*)(ws + 1050624);          // maxent*16
    size_t numoff = (1050624 + (size_t)maxent * 16 + 255) & ~(size_t)255;
    float* num = (float*)(ws + numoff);             // B*D*4
    float* den = (float*)(ws + numoff + (size_t)B * D * 4);

    esa_prep_all<<<PREP_GRID, 512, 0, stream>>>(W1, W2, b1, b2, db, T, B,
                                                W1p, W12p, b12, entries, maxent,
                                                num);
    esa_fused<<<maxent, 512, 0, stream>>>(x, gamma, beta, W1p, W12p, b1, b12,
                                          entries, num, den);
    esa_finalize<<<(B * D + 255) / 256, 256, 0, stream>>>(num, den, out, B * D);
}